// Round 13
// baseline (349.046 us; speedup 1.0000x reference)
//
#include <hip/hip_runtime.h>

#define VQ_B 32
#define VQ_D 64
#define VQ_L 4096
#define VQ_N 1024
#define VQ_R (VQ_B * VQ_L)            /* 131072 rows */
#define VQ_ZQ ((size_t)VQ_R * VQ_D)   /* 8388608 z_q elements */
#define MAIN_BLOCK 256
#define MAIN_GRID (VQ_R / MAIN_BLOCK) /* 512 */
#define CAND_CAP 16
#define EPSREL 4.5e-3f                /* >= 2^-7.98 true bf16-mfma bound */
#define RT 4                          /* row-tiles per wave (64 rows) */
#define NSEG 4                        /* code segments (blocks) */
#define SEGC (VQ_N / NSEG)            /* 256 codes per segment */
#define NCT (SEGC / 16)               /* 16 code-tiles per segment */

typedef __attribute__((ext_vector_type(16))) float f32x16;
typedef __attribute__((ext_vector_type(8)))  short short8;   /* 8 bf16 */
typedef __attribute__((ext_vector_type(4)))  float f32x4;
typedef __attribute__((ext_vector_type(4)))  unsigned int u32x4;

/* ---------- monotone float<->u32 keys ---------- */
__device__ __forceinline__ unsigned fmono(float x) {
    unsigned u = __builtin_bit_cast(unsigned, x);
    return (u & 0x80000000u) ? ~u : (u | 0x80000000u);
}
__device__ __forceinline__ float fmono_dec(unsigned k) {
    unsigned u = (k & 0x80000000u) ? (k & 0x7FFFFFFFu) : ~k;
    return __builtin_bit_cast(float, u);
}
__device__ __forceinline__ unsigned short f2bf(float x) {
    __bf16 h = (__bf16)x;  /* RNE */
    return __builtin_bit_cast(unsigned short, h);
}

/* ---------- validated numpy-pairwise norm machinery ---------- */
#define ZVE(i) ((i) < 16 ? zvA[(i) & 15] : (i) < 32 ? zvB[(i) & 15] \
               : (i) < 48 ? zvC[(i) & 15] : zvD[(i) & 15])
#define SQB(x) ({ float s_ = (x) * (x); asm volatile("" : "+v"(s_)); s_; })
#define NP_PAIRWISE64_SQ(dst)                                                  \
    do {                                                                       \
        float r0 = SQB(ZVE(0)), r1 = SQB(ZVE(1)), r2 = SQB(ZVE(2)),            \
              r3 = SQB(ZVE(3)), r4 = SQB(ZVE(4)), r5 = SQB(ZVE(5)),            \
              r6 = SQB(ZVE(6)), r7 = SQB(ZVE(7));                              \
        _Pragma("unroll")                                                      \
        for (int i_ = 1; i_ < 8; ++i_) {                                       \
            r0 += SQB(ZVE(8 * i_ + 0)); r1 += SQB(ZVE(8 * i_ + 1));            \
            r2 += SQB(ZVE(8 * i_ + 2)); r3 += SQB(ZVE(8 * i_ + 3));            \
            r4 += SQB(ZVE(8 * i_ + 4)); r5 += SQB(ZVE(8 * i_ + 5));            \
            r6 += SQB(ZVE(8 * i_ + 6)); r7 += SQB(ZVE(8 * i_ + 7));            \
        }                                                                      \
        dst = ((r0 + r1) + (r2 + r3)) + ((r4 + r5) + (r6 + r7));               \
    } while (0)

/* ---------- init: rowcnt=0, rowmin=max, nEmax=0 ---------- */
__global__ void vq_init(unsigned* __restrict__ rowcnt, unsigned* __restrict__ rowmin,
                        unsigned* __restrict__ nEmax) {
    const int i = blockIdx.x * blockDim.x + threadIdx.x;
    if (i < VQ_R) { rowcnt[i] = 0u; rowmin[i] = 0xFFFFFFFFu; }
    if (i == 0) *nEmax = 0u;
}

/* ---------- prep emb: exact nE (np chain), emb->bf16, nEmax ---------- */
__global__ void vq_prep_emb(const float* __restrict__ emb, float* __restrict__ nE,
                            unsigned short* __restrict__ emb_bf,
                            unsigned* __restrict__ nEmax) {
    const int c = blockIdx.x * blockDim.x + threadIdx.x;
    if (c >= VQ_N) return;
    const float* ec = emb + (c << 6);
    f32x16 zvA, zvB, zvC, zvD;
#pragma unroll
    for (int d = 0; d < 16; ++d) {
        zvA[d] = ec[d];
        zvB[d] = ec[d + 16];
        zvC[d] = ec[d + 32];
        zvD[d] = ec[d + 48];
    }
    float s;
    NP_PAIRWISE64_SQ(s);
    nE[c] = s;
    atomicMax(nEmax, fmono(s));
#pragma unroll
    for (int d = 0; d < 64; ++d) emb_bf[(c << 6) + d] = f2bf(ec[d]);
}

/* ---------- prep z: row-major bf16 (all 64 elems) + fp32 srow ---------- */
__global__ __launch_bounds__(256) void vq_prep_z(
    const float* __restrict__ z, unsigned short* __restrict__ z_bf,
    float* __restrict__ srow) {
    const int r = blockIdx.x * 256 + threadIdx.x;
    const int b = r >> 12;
    const int l = r & (VQ_L - 1);
    const float* zp = z + ((size_t)b << 18) + l;
    unsigned short* o = z_bf + ((size_t)r << 6);
    float s = 0.0f;
#pragma unroll
    for (int j8 = 0; j8 < 8; ++j8) {
        unsigned w[4];
#pragma unroll
        for (int p = 0; p < 4; ++p) {
            const float v0 = zp[(size_t)(j8 * 8 + 2 * p) << 12];
            const float v1 = zp[(size_t)(j8 * 8 + 2 * p + 1) << 12];
            s = __builtin_fmaf(v0, v0, s);
            s = __builtin_fmaf(v1, v1, s);
            w[p] = (unsigned)f2bf(v0) | ((unsigned)f2bf(v1) << 16);
        }
        *(u32x4*)(o + j8 * 8) = (u32x4){w[0], w[1], w[2], w[3]};
    }
    srow[r] = s;
}

/* ---------- MFMA screen: 256 rows/block x 256 codes/block ----------
   Grid (VQ_R/256, NSEG): 2048 blocks -> ~6-8 blocks/CU (round-12 fix:
   grid was 512 = 2 blocks/CU = latency-exposed). Wave = 64 rows (RT=4
   A-tiles in registers), one b0/b1 pair feeds 8 MFMAs. g~ = nE - 2*dot
   via one deterministic fmaf on bit-identical MFMA outputs -> pass1 and
   pass2 bits match without scheduler-blocking pins.
   C layout (m89-verified): col=lane&15 (code), row=(lane>>4)*4+reg.
   PASS1: block-local per-row min over its 256 codes -> one atomicMin
   (fmono key, order-independent). PASS2: thr computed inline from
   rowmin/srow/nEmax; emit codes with g~ <= thr. */
template <int PASS>
__global__ __launch_bounds__(256, 4) void vq_gemm(
    const unsigned short* __restrict__ z_bf, const unsigned short* __restrict__ emb_bf,
    const float* __restrict__ nE, const float* __restrict__ srow,
    const unsigned* __restrict__ nEmax,
    unsigned* __restrict__ rowmin, unsigned* __restrict__ rowcnt,
    unsigned short* __restrict__ candrow) {
    __shared__ float neS[SEGC];
    const int tid = threadIdx.x;
    const int c0 = blockIdx.y * SEGC;          /* block-uniform -> scalar */
    if (tid < SEGC) neS[tid] = nE[c0 + tid];
    __syncthreads();

    const int w = tid >> 6, lane = tid & 63;
    const int cl = lane & 15, grp = lane >> 4;
    const int rowbase = blockIdx.x * 256 + w * (16 * RT);

    short8 a0[RT], a1[RT];
#pragma unroll
    for (int t = 0; t < RT; ++t) {
        const unsigned short* za = z_bf + ((size_t)(rowbase + t * 16 + cl) << 6) + grp * 8;
        a0[t] = *(const short8*)(za);
        a1[t] = *(const short8*)(za + 32);
    }

    int row_r[RT][4];
#pragma unroll
    for (int t = 0; t < RT; ++t)
#pragma unroll
        for (int reg = 0; reg < 4; ++reg)
            row_r[t][reg] = rowbase + t * 16 + grp * 4 + reg;

    float thr_r[RT][4];
    if (PASS == 2) {
        const float nem = fmono_dec(*nEmax);
#pragma unroll
        for (int t = 0; t < RT; ++t)
#pragma unroll
            for (int reg = 0; reg < 4; ++reg) {
                const int r = row_r[t][reg];
                thr_r[t][reg] = fmono_dec(rowmin[r])
                              + 8.0f * EPSREL * sqrtf(srow[r] * nem) + 2e-4f;
            }
    }

    float m[RT][4];
#pragma unroll
    for (int t = 0; t < RT; ++t)
#pragma unroll
        for (int reg = 0; reg < 4; ++reg) m[t][reg] = __builtin_inff();

    const unsigned short* ebase = emb_bf + ((size_t)(c0 + cl) << 6) + grp * 8;
#pragma unroll
    for (int ct = 0; ct < NCT; ++ct) {
        const short8 b0 = *(const short8*)(ebase + ct * 1024);
        const short8 b1 = *(const short8*)(ebase + ct * 1024 + 32);
        const float ne = neS[ct * 16 + cl];

        f32x4 acc[RT];
#pragma unroll
        for (int t = 0; t < RT; ++t) {
            acc[t] = (f32x4){0.0f, 0.0f, 0.0f, 0.0f};
            acc[t] = __builtin_amdgcn_mfma_f32_16x16x32_bf16(a0[t], b0, acc[t], 0, 0, 0);
            acc[t] = __builtin_amdgcn_mfma_f32_16x16x32_bf16(a1[t], b1, acc[t], 0, 0, 0);
        }
#pragma unroll
        for (int t = 0; t < RT; ++t) {
#pragma unroll
            for (int reg = 0; reg < 4; ++reg) {
                const float g = __builtin_fmaf(-2.0f, acc[t][reg], ne);
                if (PASS == 1) {
                    m[t][reg] = fminf(m[t][reg], g);
                } else if (g <= thr_r[t][reg]) {
                    const int c = c0 + ct * 16 + cl;
                    const unsigned idx = atomicAdd(&rowcnt[row_r[t][reg]], 1u);
                    if (idx < CAND_CAP)
                        candrow[(size_t)row_r[t][reg] * CAND_CAP + idx] = (unsigned short)c;
                }
            }
        }
    }
    if (PASS == 1) {
#pragma unroll
        for (int t = 0; t < RT; ++t)
#pragma unroll
            for (int reg = 0; reg < 4; ++reg) {
                float v = m[t][reg];
                v = fminf(v, __shfl_xor(v, 1));
                v = fminf(v, __shfl_xor(v, 2));
                v = fminf(v, __shfl_xor(v, 4));
                v = fminf(v, __shfl_xor(v, 8));
                if (cl == 0) atomicMin(&rowmin[row_r[t][reg]], fmono(v));
            }
    }
}

/* ---------- exact phase: bit-exact D for survivors, (D,c)-min ---------- */
__global__ __launch_bounds__(MAIN_BLOCK) void vq_exact(
    const float* __restrict__ z, const float* __restrict__ emb,
    const float* __restrict__ nE, const unsigned* __restrict__ rowcnt,
    const unsigned short* __restrict__ candrow, float* __restrict__ out,
    float* __restrict__ partials) {
    const int r = blockIdx.x * MAIN_BLOCK + threadIdx.x;
    const int b = r >> 12;
    const int l = r & (VQ_L - 1);
    const float* zp = z + ((size_t)b << 18) + l;

    /* szz: numpy pairwise (8 accs, d=8i+j ascending, squares pre-rounded) */
    float a8[8];
#pragma unroll
    for (int j = 0; j < 8; ++j) {
        const float v = zp[(size_t)j << 12];
        float s = v * v;
        asm volatile("" : "+v"(s));
        a8[j] = s;
    }
#pragma unroll
    for (int i = 1; i < 8; ++i) {
#pragma unroll
        for (int j = 0; j < 8; ++j) {
            const float v = zp[(size_t)(8 * i + j) << 12];
            float s = v * v;
            asm volatile("" : "+v"(s));
            a8[j] += s;
        }
    }
    const float szz = ((a8[0] + a8[1]) + (a8[2] + a8[3]))
                    + ((a8[4] + a8[5]) + (a8[6] + a8[7]));

    unsigned long long best = ~0ull;
    const unsigned cnt = rowcnt[r];
    if (cnt >= 1u && cnt <= (unsigned)CAND_CAP) {
        for (unsigned i = 0; i < cnt; ++i) {
            const int c = candrow[(size_t)r * CAND_CAP + i];
            const float* __restrict__ ec = emb + (c << 6);
            float acc = 0.0f;
#pragma unroll
            for (int k = 0; k < VQ_D; ++k)
                acc = __builtin_fmaf(zp[(size_t)k << 12], ec[k], acc);
            const float D = (szz - 2.0f * acc) + nE[c];
            const unsigned long long key = ((unsigned long long)fmono(D) << 32) | (unsigned)c;
            best = (key < best) ? key : best;
        }
    } else {  /* overflow or anomaly: validated full exact scan */
        for (int c = 0; c < VQ_N; ++c) {
            const float* __restrict__ ec = emb + (c << 6);
            float acc = 0.0f;
#pragma unroll
            for (int k = 0; k < VQ_D; ++k)
                acc = __builtin_fmaf(zp[(size_t)k << 12], ec[k], acc);
            const float D = (szz - 2.0f * acc) + nE[c];
            const unsigned long long key = ((unsigned long long)fmono(D) << 32) | (unsigned)c;
            best = (key < best) ? key : best;
        }
    }
    const int bc = (int)(best & 0xFFFFFFFFull);

    const float* __restrict__ eb = emb + (bc << 6);
    float lsum = 0.0f;
#pragma unroll
    for (int d = 0; d < VQ_D; ++d) {
        const float q = eb[d];
        const float zd = zp[(size_t)d << 12];
        out[((size_t)b << 18) + ((size_t)d << 12) + l] = q;
        const float df = q - zd;
        lsum = __builtin_fmaf(df, df, lsum);
    }
    out[VQ_ZQ + 1 + (size_t)r] = (float)bc;

#pragma unroll
    for (int off = 32; off > 0; off >>= 1)
        lsum += __shfl_down(lsum, off, 64);
    __shared__ float wsum[MAIN_BLOCK / 64];
    const int lane = threadIdx.x & 63;
    const int wid = threadIdx.x >> 6;
    if (lane == 0) wsum[wid] = lsum;
    __syncthreads();
    if (threadIdx.x == 0)
        partials[blockIdx.x] = (wsum[0] + wsum[1]) + (wsum[2] + wsum[3]);
}

__global__ void vq_final(const float* __restrict__ partials, float* __restrict__ out) {
    if (threadIdx.x == 0 && blockIdx.x == 0) {
        float s = 0.0f;
        for (int i = 0; i < MAIN_GRID; ++i) s += partials[i];
        const float mse = s / (float)VQ_ZQ;
        out[VQ_ZQ] = mse + 0.25f * mse;
    }
}

/* ================= fallback path (round-8, validated, ~335us) ========== */
__global__ void vq_norme_fb(const float* __restrict__ emb, float* __restrict__ nEf) {
    const int c = blockIdx.x * blockDim.x + threadIdx.x;
    if (c >= VQ_N) return;
    const float* ec = emb + (c << 6);
    f32x16 zvA, zvB, zvC, zvD;
#pragma unroll
    for (int d = 0; d < 16; ++d) {
        zvA[d] = ec[d]; zvB[d] = ec[d + 16]; zvC[d] = ec[d + 32]; zvD[d] = ec[d + 48];
    }
    float s;
    NP_PAIRWISE64_SQ(s);
    nEf[c] = s;
}
__global__ __launch_bounds__(256, 4) void vq_dist_fb(
    const float* __restrict__ z, const float* __restrict__ emb,
    const float* __restrict__ nEf, float2* __restrict__ cand) {
    __shared__ float zs[VQ_D * 64];
    const int w = threadIdx.x >> 6;
    const int lane = threadIdx.x & 63;
    const int r = blockIdx.x * 64 + lane;
    const int b = r >> 12;
    const int l = r & (VQ_L - 1);
    const float* zp = z + ((size_t)b << 18) + l;
#pragma unroll
    for (int j = 0; j < 16; ++j) {
        const int d = (w << 4) + j;
        zs[d * 64 + lane] = zp[(size_t)d << 12];
    }
    __syncthreads();
    float a8[8];
#pragma unroll
    for (int j = 0; j < 8; ++j) {
        const float v = zs[j * 64 + lane];
        float s = v * v; asm volatile("" : "+v"(s)); a8[j] = s;
    }
#pragma unroll
    for (int i = 1; i < 8; ++i) {
#pragma unroll
        for (int j = 0; j < 8; ++j) {
            const float v = zs[(8 * i + j) * 64 + lane];
            float s = v * v; asm volatile("" : "+v"(s)); a8[j] += s;
        }
    }
    const float szz = ((a8[0] + a8[1]) + (a8[2] + a8[3])) + ((a8[4] + a8[5]) + (a8[6] + a8[7]));
    const int c0 = __builtin_amdgcn_readfirstlane(w) * 256;
    float best = __builtin_inff();
    int bc = c0;
    for (int t = 0; t < 256; t += 16) {
        float acc[16];
#pragma unroll
        for (int j = 0; j < 16; ++j) acc[j] = 0.0f;
#pragma unroll
        for (int kk = 0; kk < VQ_D; kk += 4) {
            const float z0 = zs[(kk + 0) * 64 + lane];
            const float z1 = zs[(kk + 1) * 64 + lane];
            const float z2 = zs[(kk + 2) * 64 + lane];
            const float z3 = zs[(kk + 3) * 64 + lane];
#pragma unroll
            for (int j = 0; j < 16; ++j) {
                const float* __restrict__ ec = emb + ((c0 + t + j) << 6) + kk;
                acc[j] = __builtin_fmaf(z0, ec[0], acc[j]);
                acc[j] = __builtin_fmaf(z1, ec[1], acc[j]);
                acc[j] = __builtin_fmaf(z2, ec[2], acc[j]);
                acc[j] = __builtin_fmaf(z3, ec[3], acc[j]);
            }
        }
#pragma unroll
        for (int j = 0; j < 16; ++j) {
            const int c = c0 + t + j;
            const float dist = (szz - 2.0f * acc[j]) + nEf[c];
            if (dist < best) { best = dist; bc = c; }
        }
    }
    cand[(size_t)w * VQ_R + r] = make_float2(best, (float)bc);
}
__global__ __launch_bounds__(MAIN_BLOCK) void vq_epilogue_fb(
    const float* __restrict__ z, const float* __restrict__ emb,
    const float2* __restrict__ cand, float* __restrict__ out,
    float* __restrict__ partials) {
    const int r = blockIdx.x * MAIN_BLOCK + threadIdx.x;
    const int b = r >> 12;
    const int l = r & (VQ_L - 1);
    float best = __builtin_inff();
    int bc = 0;
#pragma unroll
    for (int seg = 0; seg < 4; ++seg) {
        const float2 cd = cand[(size_t)seg * VQ_R + r];
        if (cd.x < best) { best = cd.x; bc = (int)cd.y; }
    }
    const float* zp = z + ((size_t)b << 18) + l;
    const float* __restrict__ eb = emb + (bc << 6);
    float lsum = 0.0f;
#pragma unroll
    for (int d = 0; d < VQ_D; ++d) {
        const float q = eb[d];
        const float zd = zp[(size_t)d << 12];
        out[((size_t)b << 18) + ((size_t)d << 12) + l] = q;
        const float df = q - zd;
        lsum = __builtin_fmaf(df, df, lsum);
    }
    out[VQ_ZQ + 1 + (size_t)r] = (float)bc;
#pragma unroll
    for (int off = 32; off > 0; off >>= 1)
        lsum += __shfl_down(lsum, off, 64);
    __shared__ float wsum[MAIN_BLOCK / 64];
    const int lane = threadIdx.x & 63;
    const int wid = threadIdx.x >> 6;
    if (lane == 0) wsum[wid] = lsum;
    __syncthreads();
    if (threadIdx.x == 0)
        partials[blockIdx.x] = (wsum[0] + wsum[1]) + (wsum[2] + wsum[3]);
}

/* ================= launch ================= */
extern "C" void kernel_launch(void* const* d_in, const int* in_sizes, int n_in,
                              void* d_out, int out_size, void* d_ws, size_t ws_size,
                              hipStream_t stream) {
    const float* z   = (const float*)d_in[0];
    const float* emb = (const float*)d_in[1];
    float* out = (float*)d_out;
    char* ws = (char*)d_ws;

    /* layout (16B-aligned) */
    unsigned short* z_bf   = (unsigned short*)(ws);                       /* 16777216 B */
    unsigned short* emb_bf = (unsigned short*)(ws + 16777216);            /*   131072 B */
    unsigned short* candrw = (unsigned short*)(ws + 16908288);            /*  4194304 B */
    unsigned*       rowmin = (unsigned*)(ws + 21102592);                  /*   524288 B */
    float*          thr    = (float*)(ws + 21626880);                     /*   524288 B (unused) */
    float*          srow   = (float*)(ws + 22151168);                     /*   524288 B */
    unsigned*       rowcnt = (unsigned*)(ws + 22675456);                  /*   524288 B */
    float*          nE     = (float*)(ws + 23199744);                     /*     4096 B */
    float*          parts  = (float*)(ws + 23203840);                     /*     2048 B */
    unsigned*       nEmax  = (unsigned*)(ws + 23205888);                  /*        4 B */
    const size_t need = 23205952;
    (void)thr;

    if (ws_size >= need) {
        vq_init<<<dim3(512), dim3(256), 0, stream>>>(rowcnt, rowmin, nEmax);
        vq_prep_emb<<<dim3(4), dim3(256), 0, stream>>>(emb, nE, emb_bf, nEmax);
        vq_prep_z<<<dim3(512), dim3(256), 0, stream>>>(z, z_bf, srow);
        vq_gemm<1><<<dim3(VQ_R / 256, NSEG), dim3(256), 0, stream>>>(
            z_bf, emb_bf, nE, srow, nEmax, rowmin, rowcnt, candrw);
        vq_gemm<2><<<dim3(VQ_R / 256, NSEG), dim3(256), 0, stream>>>(
            z_bf, emb_bf, nE, srow, nEmax, rowmin, rowcnt, candrw);
        vq_exact<<<dim3(MAIN_GRID), dim3(MAIN_BLOCK), 0, stream>>>(z, emb, nE, rowcnt,
                                                                   candrw, out, parts);
        vq_final<<<dim3(1), dim3(64), 0, stream>>>(parts, out);
    } else {
        /* validated round-8 fallback (~4.2 MB ws) */
        float* nEf = (float*)ws;
        float* partials = nEf + VQ_N;
        float2* cand = (float2*)(partials + MAIN_GRID);
        vq_norme_fb<<<dim3(4), dim3(256), 0, stream>>>(emb, nEf);
        vq_dist_fb<<<dim3(VQ_R / 64), dim3(256), 0, stream>>>(z, emb, nEf, cand);
        vq_epilogue_fb<<<dim3(MAIN_GRID), dim3(MAIN_BLOCK), 0, stream>>>(z, emb, cand, out, partials);
        vq_final<<<dim3(1), dim3(64), 0, stream>>>(partials, out);
    }
}

// Round 14
// 189.563 us; speedup vs baseline: 1.8413x; 1.8413x over previous
//
#include <hip/hip_runtime.h>

#define VQ_B 32
#define VQ_D 64
#define VQ_L 4096
#define VQ_N 1024
#define VQ_R (VQ_B * VQ_L)            /* 131072 rows */
#define VQ_ZQ ((size_t)VQ_R * VQ_D)   /* 8388608 z_q elements */
#define MAIN_BLOCK 256
#define MAIN_GRID (VQ_R / MAIN_BLOCK) /* 512 */
#define CAND_CAP 16
#define EPSREL 4.5e-3f                /* >= 2^-7.98 true bf16-mfma bound */
#define RT 4                          /* row-tiles per wave (64 rows) */
#define NSEG 4                        /* code segments (grid.y) */
#define SEGC (VQ_N / NSEG)            /* 256 codes per segment */
#define NCT (SEGC / 16)               /* 16 code-tiles per segment */

typedef __attribute__((ext_vector_type(16))) float f32x16;
typedef __attribute__((ext_vector_type(8)))  short short8;   /* 8 bf16 */
typedef __attribute__((ext_vector_type(4)))  float f32x4;
typedef __attribute__((ext_vector_type(4)))  unsigned int u32x4;

/* ---------- monotone float<->u32 keys ---------- */
__device__ __forceinline__ unsigned fmono(float x) {
    unsigned u = __builtin_bit_cast(unsigned, x);
    return (u & 0x80000000u) ? ~u : (u | 0x80000000u);
}
__device__ __forceinline__ float fmono_dec(unsigned k) {
    unsigned u = (k & 0x80000000u) ? (k & 0x7FFFFFFFu) : ~k;
    return __builtin_bit_cast(float, u);
}
__device__ __forceinline__ unsigned short f2bf(float x) {
    __bf16 h = (__bf16)x;  /* RNE */
    return __builtin_bit_cast(unsigned short, h);
}

/* ---------- validated numpy-pairwise norm machinery ---------- */
#define ZVE(i) ((i) < 16 ? zvA[(i) & 15] : (i) < 32 ? zvB[(i) & 15] \
               : (i) < 48 ? zvC[(i) & 15] : zvD[(i) & 15])
#define SQB(x) ({ float s_ = (x) * (x); asm volatile("" : "+v"(s_)); s_; })
#define NP_PAIRWISE64_SQ(dst)                                                  \
    do {                                                                       \
        float r0 = SQB(ZVE(0)), r1 = SQB(ZVE(1)), r2 = SQB(ZVE(2)),            \
              r3 = SQB(ZVE(3)), r4 = SQB(ZVE(4)), r5 = SQB(ZVE(5)),            \
              r6 = SQB(ZVE(6)), r7 = SQB(ZVE(7));                              \
        _Pragma("unroll")                                                      \
        for (int i_ = 1; i_ < 8; ++i_) {                                       \
            r0 += SQB(ZVE(8 * i_ + 0)); r1 += SQB(ZVE(8 * i_ + 1));            \
            r2 += SQB(ZVE(8 * i_ + 2)); r3 += SQB(ZVE(8 * i_ + 3));            \
            r4 += SQB(ZVE(8 * i_ + 4)); r5 += SQB(ZVE(8 * i_ + 5));            \
            r6 += SQB(ZVE(8 * i_ + 6)); r7 += SQB(ZVE(8 * i_ + 7));            \
        }                                                                      \
        dst = ((r0 + r1) + (r2 + r3)) + ((r4 + r5) + (r6 + r7));               \
    } while (0)

/* ---------- init: rowcnt=0, rowmin=max, nEmax=0 ---------- */
__global__ void vq_init(unsigned* __restrict__ rowcnt, unsigned* __restrict__ rowmin,
                        unsigned* __restrict__ nEmax) {
    const int i = blockIdx.x * blockDim.x + threadIdx.x;
    if (i < VQ_R) { rowcnt[i] = 0u; rowmin[i] = 0xFFFFFFFFu; }
    if (i == 0) *nEmax = 0u;
}

/* ---------- prep emb: exact nE (np chain), emb->bf16, nEmax ---------- */
__global__ void vq_prep_emb(const float* __restrict__ emb, float* __restrict__ nE,
                            unsigned short* __restrict__ emb_bf,
                            unsigned* __restrict__ nEmax) {
    const int c = blockIdx.x * blockDim.x + threadIdx.x;
    if (c >= VQ_N) return;
    const float* ec = emb + (c << 6);
    f32x16 zvA, zvB, zvC, zvD;
#pragma unroll
    for (int d = 0; d < 16; ++d) {
        zvA[d] = ec[d];
        zvB[d] = ec[d + 16];
        zvC[d] = ec[d + 32];
        zvD[d] = ec[d + 48];
    }
    float s;
    NP_PAIRWISE64_SQ(s);
    nE[c] = s;
    atomicMax(nEmax, fmono(s));
#pragma unroll
    for (int d = 0; d < 64; ++d) emb_bf[(c << 6) + d] = f2bf(ec[d]);
}

/* ---------- prep z: row-major bf16 (all 64 elems) + fp32 srow ---------- */
__global__ __launch_bounds__(256) void vq_prep_z(
    const float* __restrict__ z, unsigned short* __restrict__ z_bf,
    float* __restrict__ srow) {
    const int r = blockIdx.x * 256 + threadIdx.x;
    const int b = r >> 12;
    const int l = r & (VQ_L - 1);
    const float* zp = z + ((size_t)b << 18) + l;
    unsigned short* o = z_bf + ((size_t)r << 6);
    float s = 0.0f;
#pragma unroll
    for (int j8 = 0; j8 < 8; ++j8) {
        unsigned w[4];
#pragma unroll
        for (int p = 0; p < 4; ++p) {
            const float v0 = zp[(size_t)(j8 * 8 + 2 * p) << 12];
            const float v1 = zp[(size_t)(j8 * 8 + 2 * p + 1) << 12];
            s = __builtin_fmaf(v0, v0, s);
            s = __builtin_fmaf(v1, v1, s);
            w[p] = (unsigned)f2bf(v0) | ((unsigned)f2bf(v1) << 16);
        }
        *(u32x4*)(o + j8 * 8) = (u32x4){w[0], w[1], w[2], w[3]};
    }
    srow[r] = s;
}

/* ---------- MFMA screen: 256 rows x 256 codes per block ----------
   Round-14 = round-12's proven inner loop (dynamic ct loop, unroll 2,
   launch_bounds(256,2), VGPR~60, zero spill) + round-13's proven grid
   split (grid (512, NSEG) = 2048 blocks for occupancy). Round-13's
   regression was the FULL unroll of the ct loop + inline sqrt thr ->
   spill streaming (FETCH 455 MB, WRITE 340 MB); both reverted.
   One b0/b1 load pair feeds 8 MFMAs (4x B-reuse, round-12 win).
   C layout (m89-verified): col=lane&15 (code), row=(lane>>4)*4+reg.
   PASS1: per-row min over block's 256 codes -> atomicMin (fmono key,
   order-independent => deterministic). PASS2: load thr[row] (computed
   by vq_thr), emit codes with g~ <= thr. g~ bits identical both passes
   (same MFMA sequence + single deterministic fmaf). */
template <int PASS>
__global__ __launch_bounds__(256, 2) void vq_gemm(
    const unsigned short* __restrict__ z_bf, const unsigned short* __restrict__ emb_bf,
    const float* __restrict__ nE, const float* __restrict__ thr,
    unsigned* __restrict__ rowmin, unsigned* __restrict__ rowcnt,
    unsigned short* __restrict__ candrow) {
    __shared__ float neS[SEGC];
    const int tid = threadIdx.x;
    const int c0 = blockIdx.y * SEGC;          /* block-uniform -> scalar */
    if (tid < SEGC) neS[tid] = nE[c0 + tid];
    __syncthreads();

    const int w = tid >> 6, lane = tid & 63;
    const int cl = lane & 15, grp = lane >> 4;
    const int rowbase = blockIdx.x * 256 + w * (16 * RT);

    short8 a0[RT], a1[RT];
#pragma unroll
    for (int t = 0; t < RT; ++t) {
        const unsigned short* za = z_bf + ((size_t)(rowbase + t * 16 + cl) << 6) + grp * 8;
        a0[t] = *(const short8*)(za);
        a1[t] = *(const short8*)(za + 32);
    }

    int row_r[RT][4];
#pragma unroll
    for (int t = 0; t < RT; ++t)
#pragma unroll
        for (int reg = 0; reg < 4; ++reg)
            row_r[t][reg] = rowbase + t * 16 + grp * 4 + reg;

    float thr_r[RT][4];
    if (PASS == 2) {
#pragma unroll
        for (int t = 0; t < RT; ++t)
#pragma unroll
            for (int reg = 0; reg < 4; ++reg)
                thr_r[t][reg] = thr[row_r[t][reg]];
    }

    float m[RT][4];
#pragma unroll
    for (int t = 0; t < RT; ++t)
#pragma unroll
        for (int reg = 0; reg < 4; ++reg) m[t][reg] = __builtin_inff();

    const unsigned short* ebase = emb_bf + ((size_t)(c0 + cl) << 6) + grp * 8;
#pragma unroll 2
    for (int ct = 0; ct < NCT; ++ct) {
        const short8 b0 = *(const short8*)(ebase + ct * 1024);
        const short8 b1 = *(const short8*)(ebase + ct * 1024 + 32);
        const float ne = neS[ct * 16 + cl];

        f32x4 acc[RT];
#pragma unroll
        for (int t = 0; t < RT; ++t) {
            acc[t] = (f32x4){0.0f, 0.0f, 0.0f, 0.0f};
            acc[t] = __builtin_amdgcn_mfma_f32_16x16x32_bf16(a0[t], b0, acc[t], 0, 0, 0);
            acc[t] = __builtin_amdgcn_mfma_f32_16x16x32_bf16(a1[t], b1, acc[t], 0, 0, 0);
        }
#pragma unroll
        for (int t = 0; t < RT; ++t) {
#pragma unroll
            for (int reg = 0; reg < 4; ++reg) {
                const float g = __builtin_fmaf(-2.0f, acc[t][reg], ne);
                if (PASS == 1) {
                    m[t][reg] = fminf(m[t][reg], g);
                } else if (g <= thr_r[t][reg]) {
                    const int c = c0 + ct * 16 + cl;
                    const unsigned idx = atomicAdd(&rowcnt[row_r[t][reg]], 1u);
                    if (idx < CAND_CAP)
                        candrow[(size_t)row_r[t][reg] * CAND_CAP + idx] = (unsigned short)c;
                }
            }
        }
    }
    if (PASS == 1) {
#pragma unroll
        for (int t = 0; t < RT; ++t)
#pragma unroll
            for (int reg = 0; reg < 4; ++reg) {
                float v = m[t][reg];
                v = fminf(v, __shfl_xor(v, 1));
                v = fminf(v, __shfl_xor(v, 2));
                v = fminf(v, __shfl_xor(v, 4));
                v = fminf(v, __shfl_xor(v, 8));
                if (cl == 0) atomicMin(&rowmin[row_r[t][reg]], fmono(v));
            }
    }
}

/* ---------- thresholds: thr = gmin + rigorous margin ---------- */
__global__ void vq_thr(const unsigned* __restrict__ rowmin, const float* __restrict__ srow,
                       const unsigned* __restrict__ nEmax, float* __restrict__ thr) {
    const int r = blockIdx.x * blockDim.x + threadIdx.x;
    if (r >= VQ_R) return;
    const float nem = fmono_dec(*nEmax);
    const float margin = 8.0f * EPSREL * sqrtf(srow[r] * nem) + 2e-4f;
    thr[r] = fmono_dec(rowmin[r]) + margin;
}

/* ---------- exact phase: bit-exact D for survivors, (D,c)-min ---------- */
__global__ __launch_bounds__(MAIN_BLOCK) void vq_exact(
    const float* __restrict__ z, const float* __restrict__ emb,
    const float* __restrict__ nE, const unsigned* __restrict__ rowcnt,
    const unsigned short* __restrict__ candrow, float* __restrict__ out,
    float* __restrict__ partials) {
    const int r = blockIdx.x * MAIN_BLOCK + threadIdx.x;
    const int b = r >> 12;
    const int l = r & (VQ_L - 1);
    const float* zp = z + ((size_t)b << 18) + l;

    /* szz: numpy pairwise (8 accs, d=8i+j ascending, squares pre-rounded) */
    float a8[8];
#pragma unroll
    for (int j = 0; j < 8; ++j) {
        const float v = zp[(size_t)j << 12];
        float s = v * v;
        asm volatile("" : "+v"(s));
        a8[j] = s;
    }
#pragma unroll
    for (int i = 1; i < 8; ++i) {
#pragma unroll
        for (int j = 0; j < 8; ++j) {
            const float v = zp[(size_t)(8 * i + j) << 12];
            float s = v * v;
            asm volatile("" : "+v"(s));
            a8[j] += s;
        }
    }
    const float szz = ((a8[0] + a8[1]) + (a8[2] + a8[3]))
                    + ((a8[4] + a8[5]) + (a8[6] + a8[7]));

    unsigned long long best = ~0ull;
    const unsigned cnt = rowcnt[r];
    if (cnt >= 1u && cnt <= (unsigned)CAND_CAP) {
        for (unsigned i = 0; i < cnt; ++i) {
            const int c = candrow[(size_t)r * CAND_CAP + i];
            const float* __restrict__ ec = emb + (c << 6);
            float acc = 0.0f;
#pragma unroll
            for (int k = 0; k < VQ_D; ++k)
                acc = __builtin_fmaf(zp[(size_t)k << 12], ec[k], acc);
            const float D = (szz - 2.0f * acc) + nE[c];
            const unsigned long long key = ((unsigned long long)fmono(D) << 32) | (unsigned)c;
            best = (key < best) ? key : best;
        }
    } else {  /* overflow or anomaly: validated full exact scan */
        for (int c = 0; c < VQ_N; ++c) {
            const float* __restrict__ ec = emb + (c << 6);
            float acc = 0.0f;
#pragma unroll
            for (int k = 0; k < VQ_D; ++k)
                acc = __builtin_fmaf(zp[(size_t)k << 12], ec[k], acc);
            const float D = (szz - 2.0f * acc) + nE[c];
            const unsigned long long key = ((unsigned long long)fmono(D) << 32) | (unsigned)c;
            best = (key < best) ? key : best;
        }
    }
    const int bc = (int)(best & 0xFFFFFFFFull);

    const float* __restrict__ eb = emb + (bc << 6);
    float lsum = 0.0f;
#pragma unroll
    for (int d = 0; d < VQ_D; ++d) {
        const float q = eb[d];
        const float zd = zp[(size_t)d << 12];
        out[((size_t)b << 18) + ((size_t)d << 12) + l] = q;
        const float df = q - zd;
        lsum = __builtin_fmaf(df, df, lsum);
    }
    out[VQ_ZQ + 1 + (size_t)r] = (float)bc;

#pragma unroll
    for (int off = 32; off > 0; off >>= 1)
        lsum += __shfl_down(lsum, off, 64);
    __shared__ float wsum[MAIN_BLOCK / 64];
    const int lane = threadIdx.x & 63;
    const int wid = threadIdx.x >> 6;
    if (lane == 0) wsum[wid] = lsum;
    __syncthreads();
    if (threadIdx.x == 0)
        partials[blockIdx.x] = (wsum[0] + wsum[1]) + (wsum[2] + wsum[3]);
}

__global__ void vq_final(const float* __restrict__ partials, float* __restrict__ out) {
    if (threadIdx.x == 0 && blockIdx.x == 0) {
        float s = 0.0f;
        for (int i = 0; i < MAIN_GRID; ++i) s += partials[i];
        const float mse = s / (float)VQ_ZQ;
        out[VQ_ZQ] = mse + 0.25f * mse;
    }
}

/* ================= fallback path (round-8, validated, ~335us) ========== */
__global__ void vq_norme_fb(const float* __restrict__ emb, float* __restrict__ nEf) {
    const int c = blockIdx.x * blockDim.x + threadIdx.x;
    if (c >= VQ_N) return;
    const float* ec = emb + (c << 6);
    f32x16 zvA, zvB, zvC, zvD;
#pragma unroll
    for (int d = 0; d < 16; ++d) {
        zvA[d] = ec[d]; zvB[d] = ec[d + 16]; zvC[d] = ec[d + 32]; zvD[d] = ec[d + 48];
    }
    float s;
    NP_PAIRWISE64_SQ(s);
    nEf[c] = s;
}
__global__ __launch_bounds__(256, 4) void vq_dist_fb(
    const float* __restrict__ z, const float* __restrict__ emb,
    const float* __restrict__ nEf, float2* __restrict__ cand) {
    __shared__ float zs[VQ_D * 64];
    const int w = threadIdx.x >> 6;
    const int lane = threadIdx.x & 63;
    const int r = blockIdx.x * 64 + lane;
    const int b = r >> 12;
    const int l = r & (VQ_L - 1);
    const float* zp = z + ((size_t)b << 18) + l;
#pragma unroll
    for (int j = 0; j < 16; ++j) {
        const int d = (w << 4) + j;
        zs[d * 64 + lane] = zp[(size_t)d << 12];
    }
    __syncthreads();
    float a8[8];
#pragma unroll
    for (int j = 0; j < 8; ++j) {
        const float v = zs[j * 64 + lane];
        float s = v * v; asm volatile("" : "+v"(s)); a8[j] = s;
    }
#pragma unroll
    for (int i = 1; i < 8; ++i) {
#pragma unroll
        for (int j = 0; j < 8; ++j) {
            const float v = zs[(8 * i + j) * 64 + lane];
            float s = v * v; asm volatile("" : "+v"(s)); a8[j] += s;
        }
    }
    const float szz = ((a8[0] + a8[1]) + (a8[2] + a8[3])) + ((a8[4] + a8[5]) + (a8[6] + a8[7]));
    const int c0 = __builtin_amdgcn_readfirstlane(w) * 256;
    float best = __builtin_inff();
    int bc = c0;
    for (int t = 0; t < 256; t += 16) {
        float acc[16];
#pragma unroll
        for (int j = 0; j < 16; ++j) acc[j] = 0.0f;
#pragma unroll
        for (int kk = 0; kk < VQ_D; kk += 4) {
            const float z0 = zs[(kk + 0) * 64 + lane];
            const float z1 = zs[(kk + 1) * 64 + lane];
            const float z2 = zs[(kk + 2) * 64 + lane];
            const float z3 = zs[(kk + 3) * 64 + lane];
#pragma unroll
            for (int j = 0; j < 16; ++j) {
                const float* __restrict__ ec = emb + ((c0 + t + j) << 6) + kk;
                acc[j] = __builtin_fmaf(z0, ec[0], acc[j]);
                acc[j] = __builtin_fmaf(z1, ec[1], acc[j]);
                acc[j] = __builtin_fmaf(z2, ec[2], acc[j]);
                acc[j] = __builtin_fmaf(z3, ec[3], acc[j]);
            }
        }
#pragma unroll
        for (int j = 0; j < 16; ++j) {
            const int c = c0 + t + j;
            const float dist = (szz - 2.0f * acc[j]) + nEf[c];
            if (dist < best) { best = dist; bc = c; }
        }
    }
    cand[(size_t)w * VQ_R + r] = make_float2(best, (float)bc);
}
__global__ __launch_bounds__(MAIN_BLOCK) void vq_epilogue_fb(
    const float* __restrict__ z, const float* __restrict__ emb,
    const float2* __restrict__ cand, float* __restrict__ out,
    float* __restrict__ partials) {
    const int r = blockIdx.x * MAIN_BLOCK + threadIdx.x;
    const int b = r >> 12;
    const int l = r & (VQ_L - 1);
    float best = __builtin_inff();
    int bc = 0;
#pragma unroll
    for (int seg = 0; seg < 4; ++seg) {
        const float2 cd = cand[(size_t)seg * VQ_R + r];
        if (cd.x < best) { best = cd.x; bc = (int)cd.y; }
    }
    const float* zp = z + ((size_t)b << 18) + l;
    const float* __restrict__ eb = emb + (bc << 6);
    float lsum = 0.0f;
#pragma unroll
    for (int d = 0; d < VQ_D; ++d) {
        const float q = eb[d];
        const float zd = zp[(size_t)d << 12];
        out[((size_t)b << 18) + ((size_t)d << 12) + l] = q;
        const float df = q - zd;
        lsum = __builtin_fmaf(df, df, lsum);
    }
    out[VQ_ZQ + 1 + (size_t)r] = (float)bc;
#pragma unroll
    for (int off = 32; off > 0; off >>= 1)
        lsum += __shfl_down(lsum, off, 64);
    __shared__ float wsum[MAIN_BLOCK / 64];
    const int lane = threadIdx.x & 63;
    const int wid = threadIdx.x >> 6;
    if (lane == 0) wsum[wid] = lsum;
    __syncthreads();
    if (threadIdx.x == 0)
        partials[blockIdx.x] = (wsum[0] + wsum[1]) + (wsum[2] + wsum[3]);
}

/* ================= launch ================= */
extern "C" void kernel_launch(void* const* d_in, const int* in_sizes, int n_in,
                              void* d_out, int out_size, void* d_ws, size_t ws_size,
                              hipStream_t stream) {
    const float* z   = (const float*)d_in[0];
    const float* emb = (const float*)d_in[1];
    float* out = (float*)d_out;
    char* ws = (char*)d_ws;

    /* layout (16B-aligned) */
    unsigned short* z_bf   = (unsigned short*)(ws);                       /* 16777216 B */
    unsigned short* emb_bf = (unsigned short*)(ws + 16777216);            /*   131072 B */
    unsigned short* candrw = (unsigned short*)(ws + 16908288);            /*  4194304 B */
    unsigned*       rowmin = (unsigned*)(ws + 21102592);                  /*   524288 B */
    float*          thr    = (float*)(ws + 21626880);                     /*   524288 B */
    float*          srow   = (float*)(ws + 22151168);                     /*   524288 B */
    unsigned*       rowcnt = (unsigned*)(ws + 22675456);                  /*   524288 B */
    float*          nE     = (float*)(ws + 23199744);                     /*     4096 B */
    float*          parts  = (float*)(ws + 23203840);                     /*     2048 B */
    unsigned*       nEmax  = (unsigned*)(ws + 23205888);                  /*        4 B */
    const size_t need = 23205952;

    if (ws_size >= need) {
        vq_init<<<dim3(512), dim3(256), 0, stream>>>(rowcnt, rowmin, nEmax);
        vq_prep_emb<<<dim3(4), dim3(256), 0, stream>>>(emb, nE, emb_bf, nEmax);
        vq_prep_z<<<dim3(512), dim3(256), 0, stream>>>(z, z_bf, srow);
        vq_gemm<1><<<dim3(VQ_R / 256, NSEG), dim3(256), 0, stream>>>(
            z_bf, emb_bf, nE, thr, rowmin, rowcnt, candrw);
        vq_thr<<<dim3(512), dim3(256), 0, stream>>>(rowmin, srow, nEmax, thr);
        vq_gemm<2><<<dim3(VQ_R / 256, NSEG), dim3(256), 0, stream>>>(
            z_bf, emb_bf, nE, thr, rowmin, rowcnt, candrw);
        vq_exact<<<dim3(MAIN_GRID), dim3(MAIN_BLOCK), 0, stream>>>(z, emb, nE, rowcnt,
                                                                   candrw, out, parts);
        vq_final<<<dim3(1), dim3(64), 0, stream>>>(parts, out);
    } else {
        /* validated round-8 fallback (~4.2 MB ws) */
        float* nEf = (float*)ws;
        float* partials = nEf + VQ_N;
        float2* cand = (float2*)(partials + MAIN_GRID);
        vq_norme_fb<<<dim3(4), dim3(256), 0, stream>>>(emb, nEf);
        vq_dist_fb<<<dim3(VQ_R / 64), dim3(256), 0, stream>>>(z, emb, nEf, cand);
        vq_epilogue_fb<<<dim3(MAIN_GRID), dim3(MAIN_BLOCK), 0, stream>>>(z, emb, cand, out, partials);
        vq_final<<<dim3(1), dim3(64), 0, stream>>>(partials, out);
    }
}